// Round 2
// baseline (80.821 us; speedup 1.0000x reference)
//
#include <hip/hip_runtime.h>
#include <math.h>

// Problem constants (fixed by harness)
#define NN   128
#define TT   1024
#define SS   1024
#define H1D  512
#define H2D  128
#define OUTD 8
#define TCH  16     // t-chunks for NUDFT split (occupancy: 4096 waves = 4/SIMD)
#define TC   64     // t per chunk
#define SPT  8      // s-values per thread

// ws layout in floats (~17.6 MB total, ws is much larger)
#define OFF_RI   0                                  // interleaved (re,im) partials
#define OFF_FREQ (TCH*NN*SS*2)                      // 4194304
#define OFF_H1   (OFF_FREQ + NN*SS)                 // 4325376 (end 4390912)

__device__ __forceinline__ float cos_rev(float r) { return __builtin_amdgcn_cosf(r); } // cos(2*pi*r)
__device__ __forceinline__ float sin_rev(float r) { return __builtin_amdgcn_sinf(r); } // sin(2*pi*r)

// ---------------------------------------------------------------------------
// Kernel 1: partial NUDFT. Block = (t-chunk tc, batch n), 128 threads.
// Each thread owns 8 consecutive s; one hw sincos for base s, then 7
// angle-addition rotations by the per-t step (cos 2*pi*d, sin 2*pi*d) from LDS.
// Exact mod-1: frac(s*day) == frac(s*frac(day)); s*frac(day) split hi+lo by FMA.
// (re,im) kept as float2 to encourage v_pk_fma_f32.
// ---------------------------------------------------------------------------
__global__ __launch_bounds__(128) void k_nudft(const float* __restrict__ inp,
                                               float* __restrict__ ws) {
    const int tc  = blockIdx.x;   // 0..15
    const int n   = blockIdx.y;   // 0..127
    const int tid = threadIdx.x;  // 0..127

    __shared__ float4 sh[TC];     // {frac(day), x, cos(2pi d), sin(2pi d)}
    if (tid < TC) {
        const int t = tc * TC + tid;
        const float* p = inp + (size_t)(n * TT + t) * 3;
        const float x  = p[0];
        const float d  = p[2];
        const float df = d - floorf(d);            // exact for |d| < 2^23
        sh[tid] = make_float4(df, x, cos_rev(df), sin_rev(df));
    }
    __syncthreads();

    const float s0f = (float)(tid * SPT);
    float2 acc[SPT];
#pragma unroll
    for (int q = 0; q < SPT; ++q) acc[q] = make_float2(0.f, 0.f);

#pragma unroll 2
    for (int i = 0; i < TC; ++i) {
        const float4 v = sh[i];                    // broadcast read
        // r = frac(s0*df) with full fp32 precision of the fractional part
        const float p   = s0f * v.x;
        const float plo = fmaf(s0f, v.x, -p);      // exact product residual
        const float r   = (p - floorf(p)) + plo;
        float2 cs;
        cs.x = cos_rev(r);
        cs.y = sin_rev(r);
#pragma unroll
        for (int q = 0; q < SPT; ++q) {
            acc[q].x = fmaf(v.y, cs.x, acc[q].x);
            acc[q].y = fmaf(v.y, cs.y, acc[q].y);
            if (q < SPT - 1) {
                // rotate by phi = 2*pi*df : (c,s) <- (c*C - s*S, s*C + c*S)
                const float nc = fmaf(cs.y, -v.w, cs.x * v.z);
                const float ns = fmaf(cs.x,  v.w, cs.y * v.z);
                cs.x = nc; cs.y = ns;
            }
        }
    }

    // interleaved (re,im): PART[tc][n][s] as float2 -> 4 float4 stores
    float4* RI = (float4*)(ws + OFF_RI) +
                 ((((size_t)(tc * NN + n)) * SS + tid * SPT) >> 1);
#pragma unroll
    for (int q = 0; q < SPT / 2; ++q)
        RI[q] = make_float4(acc[2*q].x, acc[2*q].y, acc[2*q+1].x, acc[2*q+1].y);
}

// ---------------------------------------------------------------------------
// Kernel 2: combine t-chunk partials -> frequential = sqrt(re^2 + im^2)
// ---------------------------------------------------------------------------
__global__ __launch_bounds__(256) void k_combine1(float* __restrict__ ws) {
    const int idx = blockIdx.x * 256 + threadIdx.x;   // 0..131071 (= n*SS + s)
    const float2* P = (const float2*)(ws + OFF_RI);
    float re = 0.f, im = 0.f;
#pragma unroll
    for (int tc = 0; tc < TCH; ++tc) {
        const float2 v = P[(size_t)tc * (NN * SS) + idx];
        re += v.x; im += v.y;
    }
    ws[OFF_FREQ + idx] = sqrtf(fmaf(re, re, im * im));
}

// ---------------------------------------------------------------------------
// Kernel 3: layer-1 full-K GEMM + bias + sigmoid -> h1 (no split-K combine).
// Block: 8 n-rows x 64 j-cols, K=1024. A-tile (32 KB) in LDS, W1 rows
// streamed (L1-resident lines, 32 MB aggregate L2 traffic).
// ---------------------------------------------------------------------------
__global__ __launch_bounds__(256) void k_l1(const float* __restrict__ W1,
                                            const float* __restrict__ b1,
                                            float* __restrict__ ws) {
    const int jq = blockIdx.x;   // 0..7   j-chunk of 64
    const int nb = blockIdx.y;   // 0..15  n-chunk of 8
    const int tid = threadIdx.x;

    __shared__ float4 Al[8][256];  // 8 n-rows x 1024 k
    const float4* FQ = (const float4*)(ws + OFF_FREQ);
#pragma unroll
    for (int v = 0; v < 8; ++v) {
        const int idx = v * 256 + tid;
        const int row = idx >> 8, c4 = idx & 255;
        Al[row][c4] = FQ[(nb * 8 + row) * 256 + c4];
    }
    __syncthreads();

    const int jl = tid & 63, ng = tid >> 6;   // ng 0..3 handles 2 n each
    const int j = jq * 64 + jl;
    const float4* W1v = (const float4*)W1;
    float a0 = 0.f, a1 = 0.f;
#pragma unroll 4
    for (int k4 = 0; k4 < 256; ++k4) {
        const float4 w  = W1v[(size_t)j * 256 + k4];
        const float4 x0 = Al[ng * 2 + 0][k4];
        const float4 x1 = Al[ng * 2 + 1][k4];
        a0 = fmaf(x0.x, w.x, fmaf(x0.y, w.y, fmaf(x0.z, w.z, fmaf(x0.w, w.w, a0))));
        a1 = fmaf(x1.x, w.x, fmaf(x1.y, w.y, fmaf(x1.z, w.z, fmaf(x1.w, w.w, a1))));
    }
    const float bj = b1[j];
    float* H1 = ws + OFF_H1;
    H1[(size_t)(nb * 8 + ng * 2 + 0) * H1D + j] = 1.0f / (1.0f + __expf(-(a0 + bj)));
    H1[(size_t)(nb * 8 + ng * 2 + 1) * H1D + j] = 1.0f / (1.0f + __expf(-(a1 + bj)));
}

// ---------------------------------------------------------------------------
// Kernel 4: fused layers 2+3. Block covers 2 batches; thread (nh, j) computes
// h2[n][j]; then 8 threads per nh compute the final outputs from LDS.
// ---------------------------------------------------------------------------
__global__ __launch_bounds__(256) void k_l23(const float* __restrict__ W2,
                                             const float* __restrict__ b2,
                                             const float* __restrict__ W3,
                                             const float* __restrict__ b3,
                                             const float* __restrict__ ws,
                                             float* __restrict__ out) {
    const int nh = threadIdx.x >> 7;         // 0..1
    const int j  = threadIdx.x & 127;        // 0..127
    const int n  = blockIdx.x * 2 + nh;

    __shared__ float4 h1l[2][128];  // two h1 rows (512 floats each)
    __shared__ float  h2l[2][128];
    h1l[nh][j] = ((const float4*)(ws + OFF_H1))[n * 128 + j];
    __syncthreads();

    const float4* W2v = (const float4*)W2;
    float a = b2[j];
#pragma unroll 4
    for (int k = 0; k < 128; ++k) {
        const float4 h = h1l[nh][k];               // broadcast
        const float4 w = W2v[(size_t)j * 128 + k];
        a = fmaf(h.x, w.x, fmaf(h.y, w.y, fmaf(h.z, w.z, fmaf(h.w, w.w, a))));
    }
    h2l[nh][j] = 1.0f / (1.0f + __expf(-a));
    __syncthreads();

    if (j < OUTD) {
        float acc = b3[j];
#pragma unroll 8
        for (int q = 0; q < H2D; ++q) acc = fmaf(h2l[nh][q], W3[j * H2D + q], acc);
        out[n * OUTD + j] = acc;
    }
}

extern "C" void kernel_launch(void* const* d_in, const int* in_sizes, int n_in,
                              void* d_out, int out_size, void* d_ws, size_t ws_size,
                              hipStream_t stream) {
    (void)in_sizes; (void)n_in; (void)out_size; (void)ws_size;
    const float* inp = (const float*)d_in[0];
    const float* W1  = (const float*)d_in[1];
    const float* b1  = (const float*)d_in[2];
    const float* W2  = (const float*)d_in[3];
    const float* b2  = (const float*)d_in[4];
    const float* W3  = (const float*)d_in[5];
    const float* b3  = (const float*)d_in[6];
    float* out = (float*)d_out;
    float* ws  = (float*)d_ws;

    k_nudft   <<<dim3(TCH, NN), dim3(128), 0, stream>>>(inp, ws);
    k_combine1<<<dim3(512),     dim3(256), 0, stream>>>(ws);
    k_l1      <<<dim3(8, 16),   dim3(256), 0, stream>>>(W1, b1, ws);
    k_l23     <<<dim3(64),      dim3(256), 0, stream>>>(W2, b2, W3, b3, ws, out);
}

// Round 3
// 65.575 us; speedup vs baseline: 1.2325x; 1.2325x over previous
//
#include <hip/hip_runtime.h>
#include <math.h>

// Problem constants (fixed by harness)
#define NN   128
#define TT   1024
#define SS   1024
#define H1D  512
#define H2D  128
#define OUTD 8
#define TCH  16     // t-chunks for NUDFT split
#define TC   64     // t per chunk
#define SPT  8      // s-values per thread

// ws layout in floats (~23.9 MB)
#define OFF_RI   0                                  // (re,im) partials [tc][n][s] float2
#define OFF_FREQ (TCH*NN*SS*2)                      // 4194304: freq [n][s]
#define OFF_W1T  (OFF_FREQ + NN*SS)                 // 4325376: W1T4 [256 k4][512 j] float4
#define OFF_W2T  (OFF_W1T + H1D*SS)                 // 4849664: W2T4 [128 k4][128 j] float4
#define OFF_P1   (OFF_W2T + H2D*H1D)                // 4915200: P1 [16 kq][128 n][512 j]
// end: OFF_P1 + 16*NN*H1D = 5963776 floats

typedef float v2f __attribute__((ext_vector_type(2)));

__device__ __forceinline__ float cos_rev(float r) { return __builtin_amdgcn_cosf(r); } // cos(2*pi*r)
__device__ __forceinline__ float sin_rev(float r) { return __builtin_amdgcn_sinf(r); } // sin(2*pi*r)

// ---------------------------------------------------------------------------
// Kernel 0: float4-chunk transpose of W1 (512x1024) and W2 (128x512) so the
// GEMM kernels read weights with lane-consecutive j (coalesced).
// W1T4[k4][j] = W1[j][4k..4k+3]; likewise W2T4.
// ---------------------------------------------------------------------------
__global__ __launch_bounds__(256) void k_trans(const float4* __restrict__ W14,
                                               const float4* __restrict__ W24,
                                               float4* __restrict__ W1T4,
                                               float4* __restrict__ W2T4) {
    const int jt = blockIdx.x, kt = blockIdx.y, z = blockIdx.z;
    const int tid = threadIdx.x;
    __shared__ float4 tile[32][33];
    if (z == 0) {          // W1: 16 x 8 tiles
#pragma unroll
        for (int v = 0; v < 4; ++v) {
            const int idx = v * 256 + tid, r = idx >> 5, c = idx & 31;
            tile[r][c] = W14[(size_t)(jt * 32 + r) * 256 + kt * 32 + c];
        }
        __syncthreads();
#pragma unroll
        for (int v = 0; v < 4; ++v) {
            const int idx = v * 256 + tid, r = idx >> 5, c = idx & 31;
            W1T4[(size_t)(kt * 32 + r) * 512 + jt * 32 + c] = tile[c][r];
        }
    } else {               // W2: 4 x 4 tiles
        if (jt >= 4 || kt >= 4) return;
#pragma unroll
        for (int v = 0; v < 4; ++v) {
            const int idx = v * 256 + tid, r = idx >> 5, c = idx & 31;
            tile[r][c] = W24[(size_t)(jt * 32 + r) * 128 + kt * 32 + c];
        }
        __syncthreads();
#pragma unroll
        for (int v = 0; v < 4; ++v) {
            const int idx = v * 256 + tid, r = idx >> 5, c = idx & 31;
            W2T4[(size_t)(kt * 32 + r) * 128 + jt * 32 + c] = tile[c][r];
        }
    }
}

// ---------------------------------------------------------------------------
// Kernel 1: partial NUDFT. Block = (t-chunk tc, batch n), 128 threads.
// Thread owns 8 consecutive s; one hw sincos for base s, 7 angle-addition
// rotations by step (C,S)=(cos 2*pi*d, sin 2*pi*d). Packed-f32 inner loop:
//   T  = (C*c, S*c)                 v_pk_mul_f32  (P broadcast lo)
//   P' = (-S*s + T.lo, C*s + T.hi)  v_pk_fma_f32  (CS swapped, neg_lo, P bc hi)
//   acc += (x,x) * P'               v_pk_fma_f32  (DX broadcast hi)
// Same FMAs, same order as the scalar version -> bit-identical numerics.
// ---------------------------------------------------------------------------
__global__ __launch_bounds__(128) void k_nudft(const float* __restrict__ inp,
                                               float* __restrict__ ws) {
    const int tc  = blockIdx.x;   // 0..15
    const int n   = blockIdx.y;   // 0..127
    const int tid = threadIdx.x;  // 0..127

    __shared__ float4 sh[TC];     // {frac(day), x, cos(2pi d), sin(2pi d)}
    if (tid < TC) {
        const int t = tc * TC + tid;
        const float* p = inp + (size_t)(n * TT + t) * 3;
        const float x  = p[0];
        const float d  = p[2];
        const float df = d - floorf(d);            // exact for |d| < 2^23
        sh[tid] = make_float4(df, x, cos_rev(df), sin_rev(df));
    }
    __syncthreads();

    const float s0f = (float)(tid * SPT);
    v2f acc[SPT];
#pragma unroll
    for (int q = 0; q < SPT; ++q) acc[q] = (v2f){0.f, 0.f};

#pragma unroll 2
    for (int i = 0; i < TC; ++i) {
        const float4 v = sh[i];                    // broadcast read
        v2f DX; DX.x = v.x; DX.y = v.y;            // (df, x)
        v2f CS; CS.x = v.z; CS.y = v.w;            // (C, S)
        // r = frac(s0*df) with full fp32 precision of the fractional part
        const float p   = s0f * v.x;
        const float plo = fmaf(s0f, v.x, -p);
        const float r   = (p - floorf(p)) + plo;
        v2f P; P.x = cos_rev(r); P.y = sin_rev(r);
        asm("v_pk_fma_f32 %0, %1, %2, %0 op_sel:[1,0,0] op_sel_hi:[1,1,1]"
            : "+v"(acc[0]) : "v"(DX), "v"(P));
#pragma unroll
        for (int q = 1; q < SPT; ++q) {
            v2f T, P2;
            asm("v_pk_mul_f32 %0, %1, %2 op_sel:[0,0] op_sel_hi:[1,0]"
                : "=v"(T) : "v"(CS), "v"(P));
            asm("v_pk_fma_f32 %0, %1, %2, %3 op_sel:[1,1,0] op_sel_hi:[0,1,1] neg_lo:[1,0,0]"
                : "=v"(P2) : "v"(CS), "v"(P), "v"(T));
            asm("v_pk_fma_f32 %0, %1, %2, %0 op_sel:[1,0,0] op_sel_hi:[1,1,1]"
                : "+v"(acc[q]) : "v"(DX), "v"(P2));
            P = P2;
        }
    }

    float4* RI = (float4*)(ws + OFF_RI) +
                 ((((size_t)(tc * NN + n)) * SS + tid * SPT) >> 1);
#pragma unroll
    for (int q = 0; q < SPT / 2; ++q)
        RI[q] = make_float4(acc[2*q].x, acc[2*q].y, acc[2*q+1].x, acc[2*q+1].y);
}

// ---------------------------------------------------------------------------
// Kernel 2: combine t-chunk partials -> frequential = sqrt(re^2 + im^2)
// ---------------------------------------------------------------------------
__global__ __launch_bounds__(256) void k_combine1(float* __restrict__ ws) {
    const int idx = blockIdx.x * 256 + threadIdx.x;   // = n*SS + s
    const float2* P = (const float2*)(ws + OFF_RI);
    float re = 0.f, im = 0.f;
#pragma unroll
    for (int tc = 0; tc < TCH; ++tc) {
        const float2 v = P[(size_t)tc * (NN * SS) + idx];
        re += v.x; im += v.y;
    }
    ws[OFF_FREQ + idx] = sqrtf(fmaf(re, re, im * im));
}

// ---------------------------------------------------------------------------
// Kernel 3: layer-1 split-K GEMM, P1[kq][n][j] = sum_{k in chunk} freq*W1.
// W1T4 loads coalesced (lane-consecutive j); freq loads thread-uniform ->
// scalar s_load + v_fma(vgpr, sgpr). No LDS, no syncthreads.
// ---------------------------------------------------------------------------
__global__ __launch_bounds__(256) void k_l1(const float4* __restrict__ W1T4,
                                            const float4* __restrict__ FQ4,
                                            float* __restrict__ P1) {
    const int jb = blockIdx.x;   // 0..1
    const int nt = blockIdx.y;   // 0..7
    const int kq = blockIdx.z;   // 0..15
    const int j  = jb * 256 + threadIdx.x;

    float4 w[16];
#pragma unroll
    for (int k4 = 0; k4 < 16; ++k4)
        w[k4] = W1T4[(size_t)(kq * 16 + k4) * 512 + j];

#pragma unroll
    for (int nq = 0; nq < 16; ++nq) {
        const int nn = nt * 16 + nq;
        const float4* fq = FQ4 + (size_t)nn * 256 + kq * 16;   // uniform
        float a = 0.f;
#pragma unroll
        for (int k4 = 0; k4 < 16; ++k4) {
            const float4 q = fq[k4];
            a = fmaf(w[k4].x, q.x, fmaf(w[k4].y, q.y,
                fmaf(w[k4].z, q.z, fmaf(w[k4].w, q.w, a))));
        }
        P1[(size_t)(kq * NN + nn) * H1D + j] = a;
    }
}

// ---------------------------------------------------------------------------
// Kernel 4: per-batch tail: combine layer-1 partials + bias + sigmoid (LDS),
// layer-2 (coalesced W2T4 + LDS-broadcast h1), sigmoid, layer-3 -> out.
// ---------------------------------------------------------------------------
__global__ __launch_bounds__(128) void k_l23(const float* __restrict__ P1,
                                             const float* __restrict__ b1,
                                             const float4* __restrict__ W2T4,
                                             const float* __restrict__ b2,
                                             const float* __restrict__ W3,
                                             const float* __restrict__ b3,
                                             float* __restrict__ out) {
    const int n = blockIdx.x;
    const int tid = threadIdx.x;   // 0..127

    __shared__ float4 h1s[H1D / 4];
    __shared__ float  h2r[H2D];
    float* h1f = (float*)h1s;

#pragma unroll
    for (int c = 0; c < 4; ++c) {
        const int j = c * 128 + tid;
        float s = b1[j];
#pragma unroll
        for (int kq = 0; kq < 16; ++kq)
            s += P1[(size_t)(kq * NN + n) * H1D + j];
        h1f[j] = 1.0f / (1.0f + __expf(-s));
    }
    __syncthreads();

    float a = b2[tid];
#pragma unroll 8
    for (int k4 = 0; k4 < H1D / 4; ++k4) {
        const float4 w = W2T4[(size_t)k4 * H2D + tid];
        const float4 h = h1s[k4];                  // LDS broadcast
        a = fmaf(w.x, h.x, fmaf(w.y, h.y, fmaf(w.z, h.z, fmaf(w.w, h.w, a))));
    }
    h2r[tid] = 1.0f / (1.0f + __expf(-a));
    __syncthreads();

    if (tid < OUTD) {
        float acc = b3[tid];
#pragma unroll 8
        for (int q = 0; q < H2D; ++q)
            acc = fmaf(h2r[q], W3[tid * H2D + q], acc);
        out[n * OUTD + tid] = acc;
    }
}

extern "C" void kernel_launch(void* const* d_in, const int* in_sizes, int n_in,
                              void* d_out, int out_size, void* d_ws, size_t ws_size,
                              hipStream_t stream) {
    (void)in_sizes; (void)n_in; (void)out_size; (void)ws_size;
    const float* inp = (const float*)d_in[0];
    const float* W1  = (const float*)d_in[1];
    const float* b1  = (const float*)d_in[2];
    const float* W2  = (const float*)d_in[3];
    const float* b2  = (const float*)d_in[4];
    const float* W3  = (const float*)d_in[5];
    const float* b3  = (const float*)d_in[6];
    float* out = (float*)d_out;
    float* ws  = (float*)d_ws;

    float4* W1T4 = (float4*)(ws + OFF_W1T);
    float4* W2T4 = (float4*)(ws + OFF_W2T);

    k_trans   <<<dim3(16, 8, 2), dim3(256), 0, stream>>>((const float4*)W1, (const float4*)W2, W1T4, W2T4);
    k_nudft   <<<dim3(TCH, NN),  dim3(128), 0, stream>>>(inp, ws);
    k_combine1<<<dim3(512),      dim3(256), 0, stream>>>(ws);
    k_l1      <<<dim3(2, 8, 16), dim3(256), 0, stream>>>(W1T4, (const float4*)(ws + OFF_FREQ), ws + OFF_P1);
    k_l23     <<<dim3(NN),       dim3(128), 0, stream>>>(ws + OFF_P1, b1, W2T4, b2, W3, b3, out);
}